// Round 6
// baseline (53.027 us; speedup 1.0000x reference)
//
#include <hip/hip_runtime.h>
#include <math.h>

#define BATCH 8
#define NN 2048
#define DD 128
#define ROWS 4

typedef float vf4 __attribute__((ext_vector_type(4)));

// Kernel 1: per-row dual dot products. One 64-lane wave per row (B*N rows).
__global__ __launch_bounds__(256) void score_kernel(
    const float* __restrict__ x, const float* __restrict__ W,
    const float* __restrict__ bias,
    float* __restrict__ sl, float* __restrict__ sr) {
    int wave = (blockIdx.x * blockDim.x + threadIdx.x) >> 6;
    int lane = threadIdx.x & 63;
    if (wave >= BATCH * NN) return;
    const float* xr = x + (size_t)wave * DD;
    float x0 = xr[lane];
    float x1 = xr[lane + 64];
    float l = x0 * W[lane] + x1 * W[lane + 64];
    float r = x0 * W[DD + lane] + x1 * W[DD + lane + 64];
    #pragma unroll
    for (int off = 32; off; off >>= 1) {
        l += __shfl_xor(l, off, 64);
        r += __shfl_xor(r, off, 64);
    }
    if (lane == 0) {
        sl[wave] = l + bias[0];
        sr[wave] = r;
    }
}

// Kernel 2: out[b,i,j] = adj[b,i,j] * sigmoid(sl[b,i] + sr[b,j])
// Latency-bound fix: block owns 4 rows; ALL 8 vf4 global loads are issued
// back-to-back into registers (32 VGPRs in flight) before any compute,
// then compute + store. Grid 4096 blocks.
__global__ __launch_bounds__(256) void att_kernel(
    const float* __restrict__ adj, const float* __restrict__ sl,
    const float* __restrict__ sr, float* __restrict__ out) {
    __shared__ float s_sr[NN];
    __shared__ float s_sl[ROWS];
    const int row0 = blockIdx.x * ROWS;
    const int b = row0 >> 11;                    // batch (rows never straddle)
    const int tid = threadIdx.x;

    // Stage sr[b,:] (512 vf4) and sl[row0..row0+ROWS) into LDS.
    const vf4* srb = (const vf4*)(sr + (size_t)b * NN);
    ((vf4*)s_sr)[tid]       = srb[tid];
    ((vf4*)s_sr)[256 + tid] = srb[256 + tid];
    if (tid < ROWS) s_sl[tid] = sl[row0 + tid];
    __syncthreads();

    // Phase 1: issue all 8 independent global loads.
    vf4 a[ROWS][2];
    #pragma unroll
    for (int r = 0; r < ROWS; ++r) {
        const vf4* arow = (const vf4*)(adj + (size_t)(row0 + r) * NN);
        #pragma unroll
        for (int h = 0; h < 2; ++h)
            a[r][h] = arow[h * 256 + tid];
    }

    // Phase 2: compute + store.
    #pragma unroll
    for (int r = 0; r < ROWS; ++r) {
        const float slv = s_sl[r];
        vf4* orow = (vf4*)(out + (size_t)(row0 + r) * NN);
        #pragma unroll
        for (int h = 0; h < 2; ++h) {
            const int j4 = h * 256 + tid;
            const vf4 s4 = ((const vf4*)s_sr)[j4];
            const vf4 v = a[r][h];
            vf4 o;
            o.x = v.x * __builtin_amdgcn_rcpf(1.0f + __expf(-(slv + s4.x)));
            o.y = v.y * __builtin_amdgcn_rcpf(1.0f + __expf(-(slv + s4.y)));
            o.z = v.z * __builtin_amdgcn_rcpf(1.0f + __expf(-(slv + s4.z)));
            o.w = v.w * __builtin_amdgcn_rcpf(1.0f + __expf(-(slv + s4.w)));
            orow[j4] = o;
        }
    }
}

extern "C" void kernel_launch(void* const* d_in, const int* in_sizes, int n_in,
                              void* d_out, int out_size, void* d_ws, size_t ws_size,
                              hipStream_t stream) {
    const float* x   = (const float*)d_in[0];   // (8,2048,128)
    const float* adj = (const float*)d_in[1];   // (8,2048,2048)
    const float* W   = (const float*)d_in[2];   // (256,)
    const float* b   = (const float*)d_in[3];   // (1,)
    float* out = (float*)d_out;

    float* sl = (float*)d_ws;                   // 16384 floats
    float* sr = sl + BATCH * NN;                // 16384 floats

    // Kernel 1: 16384 waves, one per row
    int rows = BATCH * NN;
    int blocks1 = rows / 4;                     // 4096 blocks x 4 waves
    score_kernel<<<blocks1, 256, 0, stream>>>(x, W, b, sl, sr);

    // Kernel 2: 4096 blocks x 4 rows each (exact cover of 16384 rows)
    att_kernel<<<BATCH * NN / ROWS, 256, 0, stream>>>(adj, sl, sr, out);
}

// Round 7
// 49.663 us; speedup vs baseline: 1.0677x; 1.0677x over previous
//
#include <hip/hip_runtime.h>
#include <math.h>

#define BATCH 8
#define NN 2048
#define DD 128
#define ROWS 4

typedef float vf4 __attribute__((ext_vector_type(4)));

// Kernel 1: per-row dual dot products. One 64-lane wave per row (B*N rows).
__global__ __launch_bounds__(256) void score_kernel(
    const float* __restrict__ x, const float* __restrict__ W,
    const float* __restrict__ bias,
    float* __restrict__ sl, float* __restrict__ sr) {
    int wave = (blockIdx.x * blockDim.x + threadIdx.x) >> 6;
    int lane = threadIdx.x & 63;
    if (wave >= BATCH * NN) return;
    const float* xr = x + (size_t)wave * DD;
    float x0 = xr[lane];
    float x1 = xr[lane + 64];
    float l = x0 * W[lane] + x1 * W[lane + 64];
    float r = x0 * W[DD + lane] + x1 * W[DD + lane + 64];
    #pragma unroll
    for (int off = 32; off; off >>= 1) {
        l += __shfl_xor(l, off, 64);
        r += __shfl_xor(r, off, 64);
    }
    if (lane == 0) {
        sl[wave] = l + bias[0];
        sr[wave] = r;
    }
}

// Kernel 2: out[b,i,j] = adj[b,i,j] * sigmoid(sl[b,i] + sr[b,j])
// Block owns 4 rows; all 8 vf4 adj loads issued before any compute —
// pinned with sched_barrier(0) so the compiler can't sink them.
// Stores are nontemporal: out is never re-read, keep it out of L3 so
// adj stays L3-resident (round-5 profile: 66 MB fetch = half of adj
// was already being served from L3; protect and extend that).
__global__ __launch_bounds__(256) void att_kernel(
    const float* __restrict__ adj, const float* __restrict__ sl,
    const float* __restrict__ sr, float* __restrict__ out) {
    __shared__ float s_sr[NN];
    __shared__ float s_sl[ROWS];
    const int row0 = blockIdx.x * ROWS;
    const int b = row0 >> 11;                    // batch (rows never straddle)
    const int tid = threadIdx.x;

    // Stage sr[b,:] (512 vf4) and sl[row0..row0+ROWS) into LDS.
    const vf4* srb = (const vf4*)(sr + (size_t)b * NN);
    ((vf4*)s_sr)[tid]       = srb[tid];
    ((vf4*)s_sr)[256 + tid] = srb[256 + tid];
    if (tid < ROWS) s_sl[tid] = sl[row0 + tid];
    __syncthreads();

    // Phase 1: issue all 8 independent global loads.
    vf4 a[ROWS][2];
    #pragma unroll
    for (int r = 0; r < ROWS; ++r) {
        const vf4* arow = (const vf4*)(adj + (size_t)(row0 + r) * NN);
        #pragma unroll
        for (int h = 0; h < 2; ++h)
            a[r][h] = arow[h * 256 + tid];
    }
    __builtin_amdgcn_sched_barrier(0);   // keep all 8 loads in flight

    // Phase 2: compute + store (nontemporal).
    #pragma unroll
    for (int r = 0; r < ROWS; ++r) {
        const float slv = s_sl[r];
        vf4* orow = (vf4*)(out + (size_t)(row0 + r) * NN);
        #pragma unroll
        for (int h = 0; h < 2; ++h) {
            const int j4 = h * 256 + tid;
            const vf4 s4 = ((const vf4*)s_sr)[j4];
            const vf4 v = a[r][h];
            vf4 o;
            o.x = v.x * __builtin_amdgcn_rcpf(1.0f + __expf(-(slv + s4.x)));
            o.y = v.y * __builtin_amdgcn_rcpf(1.0f + __expf(-(slv + s4.y)));
            o.z = v.z * __builtin_amdgcn_rcpf(1.0f + __expf(-(slv + s4.z)));
            o.w = v.w * __builtin_amdgcn_rcpf(1.0f + __expf(-(slv + s4.w)));
            __builtin_nontemporal_store(o, orow + j4);
        }
    }
}

extern "C" void kernel_launch(void* const* d_in, const int* in_sizes, int n_in,
                              void* d_out, int out_size, void* d_ws, size_t ws_size,
                              hipStream_t stream) {
    const float* x   = (const float*)d_in[0];   // (8,2048,128)
    const float* adj = (const float*)d_in[1];   // (8,2048,2048)
    const float* W   = (const float*)d_in[2];   // (256,)
    const float* b   = (const float*)d_in[3];   // (1,)
    float* out = (float*)d_out;

    float* sl = (float*)d_ws;                   // 16384 floats
    float* sr = sl + BATCH * NN;                // 16384 floats

    // Kernel 1: 16384 waves, one per row
    int rows = BATCH * NN;
    int blocks1 = rows / 4;                     // 4096 blocks x 4 waves
    score_kernel<<<blocks1, 256, 0, stream>>>(x, W, b, sl, sr);

    // Kernel 2: 4096 blocks x 4 rows each (exact cover of 16384 rows)
    att_kernel<<<BATCH * NN / ROWS, 256, 0, stream>>>(adj, sl, sr, out);
}

// Round 8
// 49.649 us; speedup vs baseline: 1.0680x; 1.0003x over previous
//
#include <hip/hip_runtime.h>
#include <math.h>

#define BATCH 8
#define NN 2048
#define DD 128
#define ROWS 4

typedef float vf4 __attribute__((ext_vector_type(4)));

// Kernel 1: per-row dual dot products. One 64-lane wave per row (B*N rows).
__global__ __launch_bounds__(256) void score_kernel(
    const float* __restrict__ x, const float* __restrict__ W,
    const float* __restrict__ bias,
    float* __restrict__ sl, float* __restrict__ sr) {
    int wave = (blockIdx.x * blockDim.x + threadIdx.x) >> 6;
    int lane = threadIdx.x & 63;
    if (wave >= BATCH * NN) return;
    const float* xr = x + (size_t)wave * DD;
    float x0 = xr[lane];
    float x1 = xr[lane + 64];
    float l = x0 * W[lane] + x1 * W[lane + 64];
    float r = x0 * W[DD + lane] + x1 * W[DD + lane + 64];
    #pragma unroll
    for (int off = 32; off; off >>= 1) {
        l += __shfl_xor(l, off, 64);
        r += __shfl_xor(r, off, 64);
    }
    if (lane == 0) {
        sl[wave] = l + bias[0];
        sr[wave] = r;
    }
}

// Kernel 2: out[b,i,j] = adj[b,i,j] * sigmoid(sl[b,i] + sr[b,j])
// Block owns 4 rows; all 8 vf4 adj loads are force-materialized into
// registers via empty asm "+v" pins (hard IR use — the compiler cannot
// sink them; VGPR_Count must show ~60). Plain cached loads (adj enjoys
// partial L3 residency), nontemporal stores (out is never re-read).
__global__ __launch_bounds__(256) void att_kernel(
    const float* __restrict__ adj, const float* __restrict__ sl,
    const float* __restrict__ sr, float* __restrict__ out) {
    __shared__ float s_sr[NN];
    __shared__ float s_sl[ROWS];
    const int row0 = blockIdx.x * ROWS;
    const int b = row0 >> 11;                    // batch (rows never straddle)
    const int tid = threadIdx.x;

    // Stage sr[b,:] (512 vf4) and sl[row0..row0+ROWS) into LDS.
    const vf4* srb = (const vf4*)(sr + (size_t)b * NN);
    ((vf4*)s_sr)[tid]       = srb[tid];
    ((vf4*)s_sr)[256 + tid] = srb[256 + tid];
    if (tid < ROWS) s_sl[tid] = sl[row0 + tid];
    __syncthreads();

    // Phase 1: issue all 8 independent global loads, pin them live.
    vf4 a[ROWS][2];
    #pragma unroll
    for (int r = 0; r < ROWS; ++r) {
        const vf4* arow = (const vf4*)(adj + (size_t)(row0 + r) * NN);
        #pragma unroll
        for (int h = 0; h < 2; ++h)
            a[r][h] = arow[h * 256 + tid];
    }
    #pragma unroll
    for (int r = 0; r < ROWS; ++r)
        #pragma unroll
        for (int h = 0; h < 2; ++h)
            asm volatile("" : "+v"(a[r][h]));   // hard use: loads can't sink

    // Phase 2: compute + store (nontemporal).
    #pragma unroll
    for (int r = 0; r < ROWS; ++r) {
        const float slv = s_sl[r];
        vf4* orow = (vf4*)(out + (size_t)(row0 + r) * NN);
        #pragma unroll
        for (int h = 0; h < 2; ++h) {
            const int j4 = h * 256 + tid;
            const vf4 s4 = ((const vf4*)s_sr)[j4];
            const vf4 v = a[r][h];
            vf4 o;
            o.x = v.x * __builtin_amdgcn_rcpf(1.0f + __expf(-(slv + s4.x)));
            o.y = v.y * __builtin_amdgcn_rcpf(1.0f + __expf(-(slv + s4.y)));
            o.z = v.z * __builtin_amdgcn_rcpf(1.0f + __expf(-(slv + s4.z)));
            o.w = v.w * __builtin_amdgcn_rcpf(1.0f + __expf(-(slv + s4.w)));
            __builtin_nontemporal_store(o, orow + j4);
        }
    }
}

extern "C" void kernel_launch(void* const* d_in, const int* in_sizes, int n_in,
                              void* d_out, int out_size, void* d_ws, size_t ws_size,
                              hipStream_t stream) {
    const float* x   = (const float*)d_in[0];   // (8,2048,128)
    const float* adj = (const float*)d_in[1];   // (8,2048,2048)
    const float* W   = (const float*)d_in[2];   // (256,)
    const float* b   = (const float*)d_in[3];   // (1,)
    float* out = (float*)d_out;

    float* sl = (float*)d_ws;                   // 16384 floats
    float* sr = sl + BATCH * NN;                // 16384 floats

    // Kernel 1: 16384 waves, one per row
    int rows = BATCH * NN;
    int blocks1 = rows / 4;                     // 4096 blocks x 4 waves
    score_kernel<<<blocks1, 256, 0, stream>>>(x, W, b, sl, sr);

    // Kernel 2: 4096 blocks x 4 rows each (exact cover of 16384 rows)
    att_kernel<<<BATCH * NN / ROWS, 256, 0, stream>>>(adj, sl, sr, out);
}

// Round 9
// 46.713 us; speedup vs baseline: 1.1352x; 1.0629x over previous
//
#include <hip/hip_runtime.h>
#include <math.h>

#define BATCH 8
#define NN 2048
#define DD 128

typedef float vf4 __attribute__((ext_vector_type(4)));

// Kernel 1: per-row dual dot products. One 64-lane wave per row (B*N rows).
__global__ __launch_bounds__(256) void score_kernel(
    const float* __restrict__ x, const float* __restrict__ W,
    const float* __restrict__ bias,
    float* __restrict__ sl, float* __restrict__ sr) {
    int wave = (blockIdx.x * blockDim.x + threadIdx.x) >> 6;
    int lane = threadIdx.x & 63;
    if (wave >= BATCH * NN) return;
    const float* xr = x + (size_t)wave * DD;
    float x0 = xr[lane];
    float x1 = xr[lane + 64];
    float l = x0 * W[lane] + x1 * W[lane + 64];
    float r = x0 * W[DD + lane] + x1 * W[DD + lane + 64];
    #pragma unroll
    for (int off = 32; off; off >>= 1) {
        l += __shfl_xor(l, off, 64);
        r += __shfl_xor(r, off, 64);
    }
    if (lane == 0) {
        sl[wave] = l + bias[0];
        sr[wave] = r;
    }
}

// Kernel 2: out[b,i,j] = adj[b,i,j] * sigmoid(sl[b,i] + sr[b,j])
// Pure-TLP structure: one vf4 per thread, 512-thread blocks, one row per
// block, 16384 blocks. No LDS, no ILP games — latency is hidden by max
// occupancy (32 waves/CU, 32 KB of loads in flight per CU). sr is a hot
// 64 KB table (L2/L3-resident); sl is block-uniform; stores nontemporal.
__global__ __launch_bounds__(512) void att_kernel(
    const float* __restrict__ adj, const float* __restrict__ sl,
    const float* __restrict__ sr, float* __restrict__ out) {
    const int row = blockIdx.x;
    const int b = row >> 11;
    const int tid = threadIdx.x;

    const float slv = sl[row];
    const vf4 s4 = ((const vf4*)(sr + (size_t)b * NN))[tid];
    const vf4 a = ((const vf4*)(adj + (size_t)row * NN))[tid];
    vf4 o;
    o.x = a.x * __builtin_amdgcn_rcpf(1.0f + __expf(-(slv + s4.x)));
    o.y = a.y * __builtin_amdgcn_rcpf(1.0f + __expf(-(slv + s4.y)));
    o.z = a.z * __builtin_amdgcn_rcpf(1.0f + __expf(-(slv + s4.z)));
    o.w = a.w * __builtin_amdgcn_rcpf(1.0f + __expf(-(slv + s4.w)));
    __builtin_nontemporal_store(o, (vf4*)(out + (size_t)row * NN) + tid);
}

extern "C" void kernel_launch(void* const* d_in, const int* in_sizes, int n_in,
                              void* d_out, int out_size, void* d_ws, size_t ws_size,
                              hipStream_t stream) {
    const float* x   = (const float*)d_in[0];   // (8,2048,128)
    const float* adj = (const float*)d_in[1];   // (8,2048,2048)
    const float* W   = (const float*)d_in[2];   // (256,)
    const float* b   = (const float*)d_in[3];   // (1,)
    float* out = (float*)d_out;

    float* sl = (float*)d_ws;                   // 16384 floats
    float* sr = sl + BATCH * NN;                // 16384 floats

    // Kernel 1: 16384 waves, one per row
    int rows = BATCH * NN;
    int blocks1 = rows / 4;                     // 4096 blocks x 4 waves
    score_kernel<<<blocks1, 256, 0, stream>>>(x, W, b, sl, sr);

    // Kernel 2: one row per 512-thread block, one vf4 per thread.
    att_kernel<<<BATCH * NN, 512, 0, stream>>>(adj, sl, sr, out);
}